// Round 5
// baseline (5095.322 us; speedup 1.0000x reference)
//
#include <hip/hip_runtime.h>
#include <hip/hip_fp16.h>

// ---------------- types ----------------
typedef short    bf16x8 __attribute__((ext_vector_type(8)));
typedef _Float16 f16x8  __attribute__((ext_vector_type(8)));
typedef _Float16 f16x4  __attribute__((ext_vector_type(4)));
typedef float    f32x4  __attribute__((ext_vector_type(4)));

#define T_ 512
#define B_ 64
#define I_ 128
#define H_ 256
#define L_ 6
#define M_ 32768  // T*B

// ---- workspace offsets (bytes) ----
// xgp  : [2][512][16][256][12] f16 = 100663296 (permuted, bias-folded x-gates)
static constexpr size_t XGP_OFF   = 0;
static constexpr size_t X0_OFF    = 100663296;
static constexpr size_t YA_OFF    = 109051904;
static constexpr size_t YB_OFF    = 142606336;
static constexpr size_t WIH0_OFF  = 176160768;
static constexpr size_t WIHR_OFF  = 176553984;
static constexpr size_t WHH_OFF   = 184418304;
static constexpr size_t BIASG_OFF = 189136896;
static constexpr size_t BHN_OFF   = 189173760;

__device__ __forceinline__ unsigned bf16r(float f) {
  unsigned u = __builtin_bit_cast(unsigned, f);
  u += 0x7fffu + ((u >> 16) & 1u);
  return u >> 16;
}

// ---------------- prep kernels ----------------
__global__ void cvt_bf16(const float* __restrict__ s, unsigned short* __restrict__ d, int n) {
  for (int i = blockIdx.x * blockDim.x + threadIdx.x; i < n; i += gridDim.x * blockDim.x)
    d[i] = (unsigned short)bf16r(s[i]);
}

__global__ void prep_whh(const float* __restrict__ whh0, const float* __restrict__ whhr,
                         _Float16* __restrict__ out) {
  int i = blockIdx.x * 256 + threadIdx.x;              // 12*768*256 = 2359296 exact
  int ld = i / 196608, rem = i - ld * 196608;
  const float* src = (ld < 2) ? whh0 + (size_t)ld * 196608 : whhr + (size_t)(ld - 2) * 196608;
  out[i] = (_Float16)src[rem];
}

__global__ void prep_biasg(const float* __restrict__ bih0, const float* __restrict__ bhh0,
                           const float* __restrict__ bihr, const float* __restrict__ bhhr,
                           float* __restrict__ biasg, float* __restrict__ bhn) {
  int i = blockIdx.x * 256 + threadIdx.x;              // 12*1024 = 12288 exact
  int ld = i >> 10, p = i & 1023;
  const float* bi = (ld < 2) ? bih0 + ld * 768 : bihr + (ld - 2) * 768;
  const float* bh = (ld < 2) ? bhh0 + ld * 768 : bhhr + (ld - 2) * 768;
  if (p < 768) biasg[ld * 768 + p] = bi[p] + (p < 512 ? bh[p] : 0.0f);
  else         bhn[ld * 256 + (p - 768)] = bh[512 + (p - 768)];
}

// ---------------- GEMM: xg[m,g] = sum_k A[m,k]*W[g,k] + bias, scatter to xgp ----------------
__device__ __forceinline__ void llds16(const void* g, void* l) {
  __builtin_amdgcn_global_load_lds((const __attribute__((address_space(1))) void*)g,
                                   (__attribute__((address_space(3))) void*)l, 16, 0, 0);
}

__global__ __launch_bounds__(256)
void gemm_bt(const unsigned short* __restrict__ A,    // [M][K] bf16
             const unsigned short* __restrict__ Wl,   // [2][768][K] bf16
             _Float16* __restrict__ xgp,              // [2][512][16][256][12] f16
             const float* __restrict__ biasg_l,       // [2][768]
             int K) {
  const int m0 = blockIdx.x * 128;
  const int n0 = blockIdx.y * 128;
  const int d  = blockIdx.z;
  const unsigned short* W = Wl + (size_t)d * 768 * K;

  __shared__ short As[128 * 64];
  __shared__ short Bs[128 * 64];

  const int tid  = threadIdx.x;
  const int lane = tid & 63;
  const int q0   = lane >> 4, c0 = lane & 15;
  const int wv = tid >> 6;
  const int wm = wv >> 1, wn = wv & 1;   // 2x2 wave grid, 64x64 per wave

  f32x4 acc[4][4] = {};

  for (int kt = 0; kt < K; kt += 64) {
#pragma unroll
    for (int i = 0; i < 4; i++) {        // stage A tile (128x64)
      int e = i * 256 + tid;
      int r = e >> 3, c = (e & 7) << 3;
      llds16(A + (size_t)(m0 + r) * K + kt + c, &As[e * 8]);
    }
#pragma unroll
    for (int i = 0; i < 4; i++) {        // stage W tile (128x64)
      int e = i * 256 + tid;
      int r = e >> 3, c = (e & 7) << 3;
      llds16(W + (size_t)(n0 + r) * K + kt + c, &Bs[e * 8]);
    }
    __syncthreads();
#pragma unroll
    for (int kf = 0; kf < 2; ++kf) {
      bf16x8 a[4], b[4];
      const int krow = kf * 32 + (q0 << 3);
#pragma unroll
      for (int f = 0; f < 4; ++f)
        a[f] = *(const bf16x8*)&As[(wm * 64 + f * 16 + c0) * 64 + krow];
#pragma unroll
      for (int f = 0; f < 4; ++f)
        b[f] = *(const bf16x8*)&Bs[(wn * 64 + f * 16 + c0) * 64 + krow];
#pragma unroll
      for (int i = 0; i < 4; i++)
#pragma unroll
        for (int jn = 0; jn < 4; jn++)
          acc[i][jn] = __builtin_amdgcn_mfma_f32_16x16x32_bf16(a[i], b[jn], acc[i][jn], 0, 0, 0);
    }
    __syncthreads();
  }

  // epilogue: bias + scatter to xgp[d][tt][bg][tid_s][12]; slot = gate*4 + tj
  _Float16* xg_d = xgp + (size_t)d * 25165824;
  const int col0 = n0 + wn * 64 + c0;
  const int gate = col0 >> 8;
  const int wj = (col0 & 255) >> 6;
  float bias[4];
#pragma unroll
  for (int jn = 0; jn < 4; jn++) bias[jn] = biasg_l[d * 768 + col0 + jn * 16];
#pragma unroll
  for (int i = 0; i < 4; i++) {
    const int rowb = m0 + wm * 64 + i * 16 + q0 * 4;   // rows rowb..rowb+3, same tt/bg
    const int tt = rowb >> 6, bgm = (rowb & 63) >> 2;
    _Float16* dst = xg_d + ((size_t)tt * 16 + bgm) * 3072 + gate * 4;
#pragma unroll
    for (int v = 0; v < 4; v++) {
      const int tid_s = wj * 64 + v * 16 + c0;
      f16x4 pk;
#pragma unroll
      for (int jn = 0; jn < 4; jn++) pk[jn] = (_Float16)(acc[i][jn][v] + bias[jn]);
      *(f16x4*)(dst + tid_s * 12) = pk;
    }
  }
}

// ---------------- MFMA recurrent scan ----------------
// One WG = 4 chains x 1 direction -> 32 WGs. 256 threads, 1 wave/SIMD (512-reg budget).
// Wave w owns gate cols [64w,64w+64): 12 col-tiles x 8 k-tiles of W_hh in registers,
// stored as f16x8 (NO agpr pinning, NO per-use bitcast -> RA splits across the unified
// VGPR/AGPR file with zero shuttle copies; MFMA reads AGPR operands natively).
// Raw s_barrier + lgkmcnt(0) only; xg loads (2-step pipeline) and y stores stay in flight.
__global__ __launch_bounds__(256, 1)
void gru_mfma5(const _Float16* __restrict__ whh,   // [12][768][256] f16
               const float* __restrict__ bhn_all,  // [12][256]
               const __half* __restrict__ xgp,     // [2][512][16][256][12] f16
               const float* __restrict__ h0,       // [12][64][256] f32
               unsigned short* __restrict__ yout,  // [512][64][512] bf16
               float* __restrict__ dout,           // f32 out (y + h_n)
               int layer, int last) {
  const int tid = threadIdx.x, lane = tid & 63, w = tid >> 6;
  const int q0 = lane >> 4, c0 = lane & 15;
  const int bg = blockIdx.x, d = blockIdx.y, ld = layer * 2 + d;

  __shared__ __attribute__((aligned(16))) _Float16 Hs[2][16][256];  // 16KB
  char* lds = (char*)&Hs[0][0][0];

  // ---- B-frags: wf[g*4+t][kt] = W[g*256+64w+16t+c0][kt*32+q0*8 .. +8] ----
  f16x8 wf[12][8];
  {
    const _Float16* wb = whh + (size_t)ld * 196608;
#pragma unroll
    for (int g = 0; g < 3; g++)
#pragma unroll
      for (int t = 0; t < 4; t++) {
        const _Float16* rp = wb + (size_t)(g * 256 + w * 64 + t * 16 + c0) * 256 + q0 * 8;
#pragma unroll
        for (int kt = 0; kt < 8; kt++)
          wf[g * 4 + t][kt] = *(const f16x8*)(rp + kt * 32);
      }
  }

  float bhn_t[4];
#pragma unroll
  for (int t = 0; t < 4; t++) bhn_t[t] = bhn_all[ld * 256 + w * 64 + t * 16 + c0];

  float hreg[4];
#pragma unroll
  for (int t = 0; t < 4; t++)
    hreg[t] = h0[(size_t)ld * 16384 + (bg * 4 + q0) * 256 + (w * 64 + t * 16 + c0)];

  // offsets (buffer-relative, bytes)
  int aoff[8];
#pragma unroll
  for (int kt = 0; kt < 8; kt++)
    aoff[kt] = (c0 * 512 + kt * 64 + q0 * 16) ^ ((c0 & 7) << 4);
  int woff[4];
#pragma unroll
  for (int t = 0; t < 4; t++)
    woff[t] = (4 * q0 * 512 + (w * 64 + t * 16 + c0) * 2) ^ (((4 * q0) & 7) << 4);
  const int yml = tid >> 6, yjj = (tid & 63) * 4;
  const int yoff = (4 * yml * 512 + yjj * 2) ^ (((4 * yml) & 7) << 4);

  // ---- zero LDS (rows != 4m stay zero forever) ----
  {
    uint4* z = (uint4*)lds;
#pragma unroll
    for (int i = 0; i < 4; i++) z[tid + i * 256] = make_uint4(0, 0, 0, 0);
  }
  __syncthreads();
#pragma unroll
  for (int t = 0; t < 4; t++)
    *(_Float16*)(lds + woff[t]) = (_Float16)hreg[t];   // buf0 = h0

  // ---- xg 2-step pipeline ----
  const __half* xth = xgp + (size_t)d * 25165824 + ((size_t)bg * 256 + tid) * 12;
  const int ttA0 = d ? 511 : 0, ttB0 = d ? 510 : 1;
  uint4 xa4 = *(const uint4*)(xth + (size_t)ttA0 * 49152);
  uint2 xa2 = *(const uint2*)(xth + (size_t)ttA0 * 49152 + 8);
  uint4 xb4 = *(const uint4*)(xth + (size_t)ttB0 * 49152);
  uint2 xb2 = *(const uint2*)(xth + (size_t)ttB0 * 49152 + 8);

  asm volatile("s_waitcnt lgkmcnt(0)" ::: "memory");
  __builtin_amdgcn_s_barrier();

#define XF(X4, X2, g_, t_) ({                                          \
    unsigned u_ = ((g_) < 2) ? (&X4.x)[((g_) * 4 + (t_)) >> 1]         \
                             : (&X2.x)[(t_) >> 1];                     \
    u_ = ((t_) & 1) ? (u_ >> 16) : (u_ & 0xffffu);                     \
    __half2float(__ushort_as_half((unsigned short)u_)); })

#define STEP(CUR, X4, X2, S_)                                                     \
  {                                                                               \
    const int s_ = (S_);                                                          \
    const int tt_ = d ? 511 - s_ : s_;                                            \
    f32x4 ar[4] = {}, az[4] = {}, an4[4] = {};                                    \
    const char* rb_ = lds + (CUR) * 8192;                                         \
    _Pragma("unroll")                                                             \
    for (int kt = 0; kt < 8; kt++) {                                              \
      f16x8 af_ = *(const f16x8*)(rb_ + aoff[kt]);                                \
      _Pragma("unroll")                                                           \
      for (int t = 0; t < 4; t++) {                                               \
        ar[t]  = __builtin_amdgcn_mfma_f32_16x16x32_f16(af_, wf[t][kt],     ar[t],  0, 0, 0); \
        az[t]  = __builtin_amdgcn_mfma_f32_16x16x32_f16(af_, wf[4 + t][kt], az[t],  0, 0, 0); \
        an4[t] = __builtin_amdgcn_mfma_f32_16x16x32_f16(af_, wf[8 + t][kt], an4[t], 0, 0, 0); \
      }                                                                           \
    }                                                                             \
    char* wb_ = lds + (((CUR) ^ 1)) * 8192;                                       \
    _Pragma("unroll")                                                             \
    for (int t = 0; t < 4; t++) {                                                 \
      const float pr = ar[t][0] + XF(X4, X2, 0, t);                               \
      const float pz = az[t][0] + XF(X4, X2, 1, t);                               \
      const float xn = XF(X4, X2, 2, t);                                          \
      const float r = __builtin_amdgcn_rcpf(1.f + __builtin_amdgcn_exp2f(-1.44269504f * pr)); \
      const float z = __builtin_amdgcn_rcpf(1.f + __builtin_amdgcn_exp2f(-1.44269504f * pz)); \
      const float pn = xn + r * (an4[t][0] + bhn_t[t]);                           \
      const float e2 = __builtin_amdgcn_exp2f(2.88539008f * pn);                  \
      const float n = 1.f - 2.f * __builtin_amdgcn_rcpf(e2 + 1.f);                \
      const float h = n + z * (hreg[t] - n);                                      \
      hreg[t] = h;                                                                \
      *(_Float16*)(wb_ + woff[t]) = (_Float16)h;                                  \
    }                                                                             \
    {                                                                             \
      const int sp_ = (s_ + 2 <= 511) ? s_ + 2 : s_;                              \
      const int tp_ = d ? 511 - sp_ : sp_;                                        \
      X4 = *(const uint4*)(xth + (size_t)tp_ * 49152);                            \
      X2 = *(const uint2*)(xth + (size_t)tp_ * 49152 + 8);                        \
    }                                                                             \
    asm volatile("s_waitcnt lgkmcnt(0)" ::: "memory");                            \
    __builtin_amdgcn_s_barrier();                                                 \
    {                                                                             \
      f16x4 hv_ = *(const f16x4*)(lds + (((CUR) ^ 1)) * 8192 + yoff);             \
      const size_t orow_ = ((size_t)tt_ * 64 + bg * 4 + yml) * 512 + (size_t)d * 256 + yjj; \
      if (!last) {                                                                \
        unsigned r0_ = bf16r((float)hv_[0]) | (bf16r((float)hv_[1]) << 16);       \
        unsigned r1_ = bf16r((float)hv_[2]) | (bf16r((float)hv_[3]) << 16);       \
        *(uint2*)&yout[orow_] = make_uint2(r0_, r1_);                             \
      } else {                                                                    \
        *(float4*)&dout[orow_] =                                                  \
            make_float4((float)hv_[0], (float)hv_[1], (float)hv_[2], (float)hv_[3]); \
      }                                                                           \
    }                                                                             \
  }

  for (int s2 = 0; s2 < 512; s2 += 2) {
    STEP(0, xa4, xa2, s2);
    STEP(1, xb4, xb2, s2 + 1);
  }
#undef STEP
#undef XF

  // final hidden state (full f32 precision)
#pragma unroll
  for (int t = 0; t < 4; t++)
    dout[16777216 + (size_t)ld * 16384 + (bg * 4 + q0) * 256 + (w * 64 + t * 16 + c0)] = hreg[t];
}

// ---------------- launcher ----------------
extern "C" void kernel_launch(void* const* d_in, const int* in_sizes, int n_in,
                              void* d_out, int out_size, void* d_ws, size_t ws_size,
                              hipStream_t stream) {
  const float* x    = (const float*)d_in[0];
  const float* h0   = (const float*)d_in[1];
  const float* wih0 = (const float*)d_in[2];
  const float* whh0 = (const float*)d_in[3];
  const float* bih0 = (const float*)d_in[4];
  const float* bhh0 = (const float*)d_in[5];
  const float* wihr = (const float*)d_in[6];
  const float* whhr = (const float*)d_in[7];
  const float* bihr = (const float*)d_in[8];
  const float* bhhr = (const float*)d_in[9];

  char* ws = (char*)d_ws;
  _Float16*       xgp  = (_Float16*)(ws + XGP_OFF);
  unsigned short* x0   = (unsigned short*)(ws + X0_OFF);
  unsigned short* yA   = (unsigned short*)(ws + YA_OFF);
  unsigned short* yB   = (unsigned short*)(ws + YB_OFF);
  unsigned short* wih0b= (unsigned short*)(ws + WIH0_OFF);
  unsigned short* wihrb= (unsigned short*)(ws + WIHR_OFF);
  _Float16*       whhf = (_Float16*)(ws + WHH_OFF);
  float*          biasg= (float*)(ws + BIASG_OFF);
  float*          bhn  = (float*)(ws + BHN_OFF);
  float*          dout = (float*)d_out;

  cvt_bf16<<<4096, 256, 0, stream>>>(x, x0, M_ * I_);
  cvt_bf16<<<768, 256, 0, stream>>>(wih0, wih0b, 2 * 768 * 128);
  cvt_bf16<<<4096, 256, 0, stream>>>(wihr, wihrb, 5 * 2 * 768 * 512);
  prep_whh<<<9216, 256, 0, stream>>>(whh0, whhr, whhf);
  prep_biasg<<<48, 256, 0, stream>>>(bih0, bhh0, bihr, bhhr, biasg, bhn);

  for (int l = 0; l < L_; l++) {
    unsigned short* yw = (l & 1) ? yB : yA;                        // scan l writes
    const unsigned short* A = (l == 0) ? x0 : ((l & 1) ? yA : yB); // gemm l reads scan l-1 out
    const int K = (l == 0) ? 128 : 512;
    const unsigned short* W = (l == 0) ? wih0b : wihrb + (size_t)(l - 1) * 2 * 768 * 512;

    gemm_bt<<<dim3(256, 6, 2), 256, 0, stream>>>(A, W, xgp, biasg + (size_t)l * 1536, K);
    gru_mfma5<<<dim3(16, 2), 256, 0, stream>>>(whhf, bhn, (const __half*)xgp, h0, yw, dout, l,
                                               l == L_ - 1);
  }
}

// Round 6
// 3765.789 us; speedup vs baseline: 1.3531x; 1.3531x over previous
//
#include <hip/hip_runtime.h>
#include <hip/hip_fp16.h>

// ---------------- types ----------------
typedef short bf16x8 __attribute__((ext_vector_type(8)));
typedef float f32x4  __attribute__((ext_vector_type(4)));
typedef _Float16 h2_t __attribute__((ext_vector_type(2)));

#define T_ 512
#define B_ 64
#define I_ 128
#define H_ 256
#define L_ 6
#define M_ 32768  // T*B

// ---- workspace offsets (bytes), all 256-aligned ----
static constexpr size_t XG_OFF    = 0;
static constexpr size_t X0_OFF    = 100663296;
static constexpr size_t YA_OFF    = 109051904;
static constexpr size_t YB_OFF    = 142606336;
static constexpr size_t WIH0_OFF  = 176160768;
static constexpr size_t WIHR_OFF  = 176553984;
static constexpr size_t WSCAN_OFF = 184418304;
static constexpr size_t BIAS_OFF  = 189136896;

// ---------------- prep kernels ----------------
__global__ void cvt_bf16(const float* __restrict__ s, unsigned short* __restrict__ d, int n) {
  for (int i = blockIdx.x * blockDim.x + threadIdx.x; i < n; i += gridDim.x * blockDim.x) {
    unsigned u = __builtin_bit_cast(unsigned, s[i]);
    u += 0x7fffu + ((u >> 16) & 1u);
    d[i] = (unsigned short)(u >> 16);
  }
}

// wscan[ld][gate][r][j] = (f16(w_hh[gate*256+j][2r]), f16(w_hh[gate*256+j][2r+1]))
__global__ void prep_wscan(const float* __restrict__ whh0, const float* __restrict__ whhr,
                           unsigned int* __restrict__ out) {
  int idx = blockIdx.x * 256 + threadIdx.x;            // 12*3*128*256 = 1179648 exact
  int ld  = idx / 98304;
  int rem = idx - ld * 98304;
  int tg  = rem >> 15;
  int r   = (rem >> 8) & 127;
  int j   = rem & 255;
  const float* src = (ld < 2) ? (whh0 + (size_t)ld * 196608) : (whhr + (size_t)(ld - 2) * 196608);
  const float* row = src + (size_t)(tg * 256 + j) * 256;
  h2_t p; p[0] = (_Float16)row[2 * r]; p[1] = (_Float16)row[2 * r + 1];
  out[idx] = __builtin_bit_cast(unsigned int, p);
}

// bias4[ld][c][j]: c0 = bih_r+bhh_r, c1 = bih_z+bhh_z, c2 = bih_n, c3 = bhh_n
__global__ void prep_bias(const float* __restrict__ bih0, const float* __restrict__ bhh0,
                          const float* __restrict__ bihr, const float* __restrict__ bhhr,
                          float* __restrict__ out) {
  int idx = blockIdx.x * 256 + threadIdx.x;            // 12*4*256 = 12288 exact
  int ld = idx >> 10;
  int c  = (idx >> 8) & 3;
  int j  = idx & 255;
  const float* bi = (ld < 2) ? bih0 + ld * 768 : bihr + (ld - 2) * 768;
  const float* bh = (ld < 2) ? bhh0 + ld * 768 : bhhr + (ld - 2) * 768;
  float v;
  if (c == 0)      v = bi[j] + bh[j];
  else if (c == 1) v = bi[256 + j] + bh[256 + j];
  else if (c == 2) v = bi[512 + j];
  else             v = bh[512 + j];
  out[idx] = v;
}

// ---------------- GEMM: C[m,g] = sum_k A[m,k]*W[g,k], bf16 in, f16 out ----------------
__device__ __forceinline__ void llds16(const void* g, void* l) {
  __builtin_amdgcn_global_load_lds((const __attribute__((address_space(1))) void*)g,
                                   (__attribute__((address_space(3))) void*)l, 16, 0, 0);
}

__global__ __launch_bounds__(256)
void gemm_bt(const unsigned short* __restrict__ A,    // [M][K] bf16
             const unsigned short* __restrict__ Wl,   // [2][768][K] bf16
             __half* __restrict__ xg,                 // [2][M][768] f16
             int K) {
  const int m0 = blockIdx.x * 128;
  const int n0 = blockIdx.y * 128;
  const int d  = blockIdx.z;
  const unsigned short* W = Wl + (size_t)d * 768 * K;
  __half* C = xg + (size_t)d * M_ * 768;

  __shared__ short As[128 * 64];
  __shared__ short Bs[128 * 64];

  const int tid  = threadIdx.x;
  const int lane = tid & 63;

  const int wv = tid >> 6;
  const int wm = wv >> 1, wn = wv & 1;   // 2x2 wave grid, 64x64 per wave

  f32x4 acc[4][4] = {};

  for (int kt = 0; kt < K; kt += 64) {
#pragma unroll
    for (int i = 0; i < 4; i++) {        // stage A tile (128x64)
      int e = i * 256 + tid;
      int r = e >> 3, c = (e & 7) << 3;
      llds16(A + (size_t)(m0 + r) * K + kt + c, &As[e * 8]);
    }
#pragma unroll
    for (int i = 0; i < 4; i++) {        // stage W tile (128x64)
      int e = i * 256 + tid;
      int r = e >> 3, c = (e & 7) << 3;
      llds16(W + (size_t)(n0 + r) * K + kt + c, &Bs[e * 8]);
    }
    __syncthreads();
#pragma unroll
    for (int kf = 0; kf < 2; ++kf) {
      bf16x8 a[4], b[4];
      const int krow = kf * 32 + ((lane >> 4) << 3);
#pragma unroll
      for (int f = 0; f < 4; ++f)
        a[f] = *(const bf16x8*)&As[(wm * 64 + f * 16 + (lane & 15)) * 64 + krow];
#pragma unroll
      for (int f = 0; f < 4; ++f)
        b[f] = *(const bf16x8*)&Bs[(wn * 64 + f * 16 + (lane & 15)) * 64 + krow];
#pragma unroll
      for (int i = 0; i < 4; i++)
#pragma unroll
        for (int jn = 0; jn < 4; jn++)
          acc[i][jn] = __builtin_amdgcn_mfma_f32_16x16x32_bf16(a[i], b[jn], acc[i][jn], 0, 0, 0);
    }
    __syncthreads();
  }
  // epilogue: D col = lane&15, row = (lane>>4)*4 + v
#pragma unroll
  for (int i = 0; i < 4; i++) {
    const int row_b = m0 + wm * 64 + i * 16 + ((lane >> 4) << 2);
#pragma unroll
    for (int jn = 0; jn < 4; jn++) {
      const int col = n0 + wn * 64 + jn * 16 + (lane & 15);
#pragma unroll
      for (int v = 0; v < 4; ++v)
        C[(size_t)(row_b + v) * 768 + col] = __float2half(acc[i][jn][v]);
    }
  }
}

// ---------------- recurrent scan: one WG per (b, dir) chain ----------------
// 512 threads: thread (j, half) owns gates r/z/n for column j over k in
// [half*128, half*128+128). Weights: 3*64 = 192 u32 per thread, made
// register-RESIDENT by opaque empty-asm defs (blocks LLVM's load-remat,
// which in round 2 re-streamed ~300 KB/WG/step from L2 -> VGPR_Count=116,
// 2740 cy/step). Partner (K-half) reduce via DPP quad-perm.
#define FDOT2(a, b, c) __builtin_amdgcn_fdot2((a), (b), (c), false)

__device__ __forceinline__ float dpp_xor1(float x) {
  // quad_perm [1,0,3,2] = 0xB1 : swap adjacent lanes (VALU pipe, not LDS)
  int r = __builtin_amdgcn_update_dpp(0, __builtin_bit_cast(int, x), 0xB1, 0xF, 0xF, true);
  return __builtin_bit_cast(float, r);
}

__global__ __launch_bounds__(512, 2)
void gru_scan2(const unsigned int* __restrict__ wscan,  // [12][3][128][256]
               const float* __restrict__ bias4,         // [12][4][256]
               const __half* __restrict__ xg,           // [2][M][768]
               const float* __restrict__ h0,            // [12][64][256]
               unsigned short* __restrict__ yout,       // [M][512] bf16 (next-layer input)
               float* __restrict__ dout,                // d_out base (f32)
               int layer, int last) {
  const int tid  = threadIdx.x;
  const int j    = tid >> 1;   // h column / gate triple owner
  const int half = tid & 1;    // K-half
  const int b    = blockIdx.x; // batch
  const int d    = blockIdx.y; // direction
  const int ld   = layer * 2 + d;

  // w_hh rows (r,z,n for column j, k-half) -> 192 u32 in registers
  unsigned int wr[64], wz[64], wn_[64];
  {
    const unsigned int* wb = wscan + (size_t)ld * 98304 + (size_t)half * 64 * 256 + j;
#pragma unroll
    for (int r = 0; r < 64; r++) wr[r]  = wb[r * 256];
#pragma unroll
    for (int r = 0; r < 64; r++) wz[r]  = wb[32768 + r * 256];
#pragma unroll
    for (int r = 0; r < 64; r++) wn_[r] = wb[65536 + r * 256];
  }
  // Opaque redefinition: kills rematerialization, forces true residency.
#pragma unroll
  for (int r = 0; r < 64; r++) {
    asm volatile("" : "+v"(wr[r]));
    asm volatile("" : "+v"(wz[r]));
    asm volatile("" : "+v"(wn_[r]));
  }

  const float* bb = bias4 + ld * 1024;
  const float bR = bb[j], bZ = bb[256 + j], bXn = bb[512 + j], bHn = bb[768 + j];

  __shared__ __attribute__((aligned(16))) unsigned short hb[2][256];

  float h = h0[(size_t)ld * 16384 + b * 256 + j];
  if (half == 0) hb[0][j] = __half_as_ushort(__float2half(h));

  const __half* xgd = xg + (size_t)d * M_ * 768;
  const int t0 = d ? 511 : 0;
  size_t xb = (size_t)(t0 * 64 + b) * 768 + j;
  __half cxr = xgd[xb], cxz = xgd[xb + 256], cxn = xgd[xb + 512];

  __syncthreads();

  for (int s = 0; s < 512; s++) {
    const int cur = s & 1;
    // prefetch next step's xg
    const int sn = (s + 1) & 511;
    const int t1 = d ? 511 - sn : sn;
    const size_t xb1 = (size_t)(t1 * 64 + b) * 768 + j;
    const __half nxr = xgd[xb1], nxz = xgd[xb1 + 256], nxn = xgd[xb1 + 512];

    float ar = 0.f, az = 0.f, an = 0.f;
    const uint4* hp = (const uint4*)(&hb[cur][half << 7]);
#pragma unroll
    for (int q = 0; q < 16; q++) {
      const uint4 hv = hp[q];
      const h2_t p0 = __builtin_bit_cast(h2_t, hv.x);
      const h2_t p1 = __builtin_bit_cast(h2_t, hv.y);
      const h2_t p2 = __builtin_bit_cast(h2_t, hv.z);
      const h2_t p3 = __builtin_bit_cast(h2_t, hv.w);
      ar = FDOT2(p0, __builtin_bit_cast(h2_t, wr[4 * q + 0]), ar);
      az = FDOT2(p0, __builtin_bit_cast(h2_t, wz[4 * q + 0]), az);
      an = FDOT2(p0, __builtin_bit_cast(h2_t, wn_[4 * q + 0]), an);
      ar = FDOT2(p1, __builtin_bit_cast(h2_t, wr[4 * q + 1]), ar);
      az = FDOT2(p1, __builtin_bit_cast(h2_t, wz[4 * q + 1]), az);
      an = FDOT2(p1, __builtin_bit_cast(h2_t, wn_[4 * q + 1]), an);
      ar = FDOT2(p2, __builtin_bit_cast(h2_t, wr[4 * q + 2]), ar);
      az = FDOT2(p2, __builtin_bit_cast(h2_t, wz[4 * q + 2]), az);
      an = FDOT2(p2, __builtin_bit_cast(h2_t, wn_[4 * q + 2]), an);
      ar = FDOT2(p3, __builtin_bit_cast(h2_t, wr[4 * q + 3]), ar);
      az = FDOT2(p3, __builtin_bit_cast(h2_t, wz[4 * q + 3]), az);
      an = FDOT2(p3, __builtin_bit_cast(h2_t, wn_[4 * q + 3]), an);
    }
    // combine K-halves: partner is the adjacent lane
    ar += dpp_xor1(ar);
    az += dpp_xor1(az);
    an += dpp_xor1(an);

    const float prer = ar + __half2float(cxr) + bR;
    const float prez = az + __half2float(cxz) + bZ;
    const float r = __builtin_amdgcn_rcpf(1.f + __builtin_amdgcn_exp2f(-1.44269504f * prer));
    const float z = __builtin_amdgcn_rcpf(1.f + __builtin_amdgcn_exp2f(-1.44269504f * prez));
    const float pren = __half2float(cxn) + bXn + r * (an + bHn);
    const float e2 = __builtin_amdgcn_exp2f(2.88539008f * pren);
    const float n = 1.f - 2.f * __builtin_amdgcn_rcpf(e2 + 1.f);
    h = n + z * (h - n);

    if (half == 0) {
      hb[cur ^ 1][j] = __half_as_ushort(__float2half(h));
      const int t = d ? 511 - s : s;
      const size_t orow = (size_t)(t * 64 + b) * 512 + (size_t)d * 256 + j;
      if (last) {
        dout[orow] = h;
      } else {
        unsigned u = __builtin_bit_cast(unsigned, h);
        u += 0x7fffu + ((u >> 16) & 1u);
        yout[orow] = (unsigned short)(u >> 16);
      }
    }
    cxr = nxr; cxz = nxz; cxn = nxn;
    __syncthreads();
  }
  // final hidden state -> h_n region
  if (half == 0) dout[16777216 + (size_t)ld * 16384 + b * 256 + j] = h;
}

// ---------------- launcher ----------------
extern "C" void kernel_launch(void* const* d_in, const int* in_sizes, int n_in,
                              void* d_out, int out_size, void* d_ws, size_t ws_size,
                              hipStream_t stream) {
  const float* x    = (const float*)d_in[0];
  const float* h0   = (const float*)d_in[1];
  const float* wih0 = (const float*)d_in[2];
  const float* whh0 = (const float*)d_in[3];
  const float* bih0 = (const float*)d_in[4];
  const float* bhh0 = (const float*)d_in[5];
  const float* wihr = (const float*)d_in[6];
  const float* whhr = (const float*)d_in[7];
  const float* bihr = (const float*)d_in[8];
  const float* bhhr = (const float*)d_in[9];

  char* ws = (char*)d_ws;
  __half*        xg    = (__half*)(ws + XG_OFF);
  unsigned short* x0   = (unsigned short*)(ws + X0_OFF);
  unsigned short* yA   = (unsigned short*)(ws + YA_OFF);
  unsigned short* yB   = (unsigned short*)(ws + YB_OFF);
  unsigned short* wih0b= (unsigned short*)(ws + WIH0_OFF);
  unsigned short* wihrb= (unsigned short*)(ws + WIHR_OFF);
  unsigned int*  wscan = (unsigned int*)(ws + WSCAN_OFF);
  float*         bias4 = (float*)(ws + BIAS_OFF);
  float*         dout  = (float*)d_out;

  cvt_bf16<<<4096, 256, 0, stream>>>(x, x0, M_ * I_);
  cvt_bf16<<<768, 256, 0, stream>>>(wih0, wih0b, 2 * 768 * 128);
  cvt_bf16<<<4096, 256, 0, stream>>>(wihr, wihrb, 5 * 2 * 768 * 512);
  prep_wscan<<<4608, 256, 0, stream>>>(whh0, whhr, wscan);
  prep_bias<<<48, 256, 0, stream>>>(bih0, bhh0, bihr, bhhr, bias4);

  for (int l = 0; l < L_; l++) {
    unsigned short* yw = (l & 1) ? yB : yA;                        // scan l writes
    const unsigned short* A = (l == 0) ? x0 : ((l & 1) ? yA : yB); // gemm l reads scan l-1's out
    const int K = (l == 0) ? 128 : 512;
    const unsigned short* W = (l == 0) ? wih0b : wihrb + (size_t)(l - 1) * 2 * 768 * 512;

    gemm_bt<<<dim3(256, 6, 2), 256, 0, stream>>>(A, W, xg, K);
    gru_scan2<<<dim3(64, 2), 512, 0, stream>>>(wscan, bias4, xg, h0, yw, dout, l, l == L_ - 1);
  }
}

// Round 7
// 3733.081 us; speedup vs baseline: 1.3649x; 1.0088x over previous
//
#include <hip/hip_runtime.h>
#include <hip/hip_fp16.h>

// ---------------- types ----------------
typedef short bf16x8 __attribute__((ext_vector_type(8)));
typedef float f32x4  __attribute__((ext_vector_type(4)));
typedef _Float16 h2_t __attribute__((ext_vector_type(2)));

#define T_ 512
#define B_ 64
#define I_ 128
#define H_ 256
#define L_ 6
#define M_ 32768  // T*B

// ---- workspace offsets (bytes), all 256-aligned ----
static constexpr size_t XG_OFF    = 0;
static constexpr size_t X0_OFF    = 100663296;
static constexpr size_t YA_OFF    = 109051904;
static constexpr size_t YB_OFF    = 142606336;
static constexpr size_t WIH0_OFF  = 176160768;
static constexpr size_t WIHR_OFF  = 176553984;
static constexpr size_t WSCAN_OFF = 184418304;
static constexpr size_t BIAS_OFF  = 189136896;

// ---------------- prep kernels ----------------
__global__ void cvt_bf16(const float* __restrict__ s, unsigned short* __restrict__ d, int n) {
  for (int i = blockIdx.x * blockDim.x + threadIdx.x; i < n; i += gridDim.x * blockDim.x) {
    unsigned u = __builtin_bit_cast(unsigned, s[i]);
    u += 0x7fffu + ((u >> 16) & 1u);
    d[i] = (unsigned short)(u >> 16);
  }
}

// wscan[ld][gate][r][j] = (f16(w_hh[gate*256+j][2r]), f16(w_hh[gate*256+j][2r+1]))
__global__ void prep_wscan(const float* __restrict__ whh0, const float* __restrict__ whhr,
                           unsigned int* __restrict__ out) {
  int idx = blockIdx.x * 256 + threadIdx.x;            // 12*3*128*256 = 1179648 exact
  int ld  = idx / 98304;
  int rem = idx - ld * 98304;
  int tg  = rem >> 15;
  int r   = (rem >> 8) & 127;
  int j   = rem & 255;
  const float* src = (ld < 2) ? (whh0 + (size_t)ld * 196608) : (whhr + (size_t)(ld - 2) * 196608);
  const float* row = src + (size_t)(tg * 256 + j) * 256;
  h2_t p; p[0] = (_Float16)row[2 * r]; p[1] = (_Float16)row[2 * r + 1];
  out[idx] = __builtin_bit_cast(unsigned int, p);
}

// bias4[ld][c][j]: c0 = bih_r+bhh_r, c1 = bih_z+bhh_z, c2 = bih_n, c3 = bhh_n
__global__ void prep_bias(const float* __restrict__ bih0, const float* __restrict__ bhh0,
                          const float* __restrict__ bihr, const float* __restrict__ bhhr,
                          float* __restrict__ out) {
  int idx = blockIdx.x * 256 + threadIdx.x;            // 12*4*256 = 12288 exact
  int ld = idx >> 10;
  int c  = (idx >> 8) & 3;
  int j  = idx & 255;
  const float* bi = (ld < 2) ? bih0 + ld * 768 : bihr + (ld - 2) * 768;
  const float* bh = (ld < 2) ? bhh0 + ld * 768 : bhhr + (ld - 2) * 768;
  float v;
  if (c == 0)      v = bi[j] + bh[j];
  else if (c == 1) v = bi[256 + j] + bh[256 + j];
  else if (c == 2) v = bi[512 + j];
  else             v = bh[512 + j];
  out[idx] = v;
}

// ---------------- GEMM: C[m,g] = sum_k A[m,k]*W[g,k], bf16 in, f16 out ----------------
__device__ __forceinline__ void llds16(const void* g, void* l) {
  __builtin_amdgcn_global_load_lds((const __attribute__((address_space(1))) void*)g,
                                   (__attribute__((address_space(3))) void*)l, 16, 0, 0);
}

__global__ __launch_bounds__(256)
void gemm_bt(const unsigned short* __restrict__ A,    // [M][K] bf16
             const unsigned short* __restrict__ Wl,   // [2][768][K] bf16
             __half* __restrict__ xg,                 // [2][M][768] f16
             int K) {
  const int m0 = blockIdx.x * 128;
  const int n0 = blockIdx.y * 128;
  const int d  = blockIdx.z;
  const unsigned short* W = Wl + (size_t)d * 768 * K;
  __half* C = xg + (size_t)d * M_ * 768;

  __shared__ short As[128 * 64];
  __shared__ short Bs[128 * 64];

  const int tid  = threadIdx.x;
  const int lane = tid & 63;

  const int wv = tid >> 6;
  const int wm = wv >> 1, wn = wv & 1;   // 2x2 wave grid, 64x64 per wave

  f32x4 acc[4][4] = {};

  for (int kt = 0; kt < K; kt += 64) {
#pragma unroll
    for (int i = 0; i < 4; i++) {        // stage A tile (128x64)
      int e = i * 256 + tid;
      int r = e >> 3, c = (e & 7) << 3;
      llds16(A + (size_t)(m0 + r) * K + kt + c, &As[e * 8]);
    }
#pragma unroll
    for (int i = 0; i < 4; i++) {        // stage W tile (128x64)
      int e = i * 256 + tid;
      int r = e >> 3, c = (e & 7) << 3;
      llds16(W + (size_t)(n0 + r) * K + kt + c, &Bs[e * 8]);
    }
    __syncthreads();
#pragma unroll
    for (int kf = 0; kf < 2; ++kf) {
      bf16x8 a[4], b[4];
      const int krow = kf * 32 + ((lane >> 4) << 3);
#pragma unroll
      for (int f = 0; f < 4; ++f)
        a[f] = *(const bf16x8*)&As[(wm * 64 + f * 16 + (lane & 15)) * 64 + krow];
#pragma unroll
      for (int f = 0; f < 4; ++f)
        b[f] = *(const bf16x8*)&Bs[(wn * 64 + f * 16 + (lane & 15)) * 64 + krow];
#pragma unroll
      for (int i = 0; i < 4; i++)
#pragma unroll
        for (int jn = 0; jn < 4; jn++)
          acc[i][jn] = __builtin_amdgcn_mfma_f32_16x16x32_bf16(a[i], b[jn], acc[i][jn], 0, 0, 0);
    }
    __syncthreads();
  }
  // epilogue: D col = lane&15, row = (lane>>4)*4 + v
#pragma unroll
  for (int i = 0; i < 4; i++) {
    const int row_b = m0 + wm * 64 + i * 16 + ((lane >> 4) << 2);
#pragma unroll
    for (int jn = 0; jn < 4; jn++) {
      const int col = n0 + wn * 64 + jn * 16 + (lane & 15);
#pragma unroll
      for (int v = 0; v < 4; ++v)
        C[(size_t)(row_b + v) * 768 + col] = __float2half(acc[i][jn][v]);
    }
  }
}

// ---------------- recurrent scan: one WG per (b, dir) chain ----------------
// 512 threads: thread (j, half) owns gates r/z/n for column j over k in
// [half*128, half*128+128). 192 weight u32/thread kept register-RESIDENT:
//  - __launch_bounds__(512, 1): 1 block/CU -> 2 waves/SIMD -> 256-reg budget
//    (round 2/6 used (512,2) which acted as 2 blocks/CU -> 128-reg cap -> spills).
//  - accumulator-tied fences cap in-flight LDS lines at ~5 (peak pressure ~240).
//  - bit-4 XOR swizzle on the upper 256B half kills the 2-line bank aliasing
//    (3.35e7 conflict-cycles in r6).
#define FDOT2(a, b, c) __builtin_amdgcn_fdot2((a), (b), (c), false)
#define BC2(u) __builtin_bit_cast(h2_t, (u))

__device__ __forceinline__ float dpp_xor1(float x) {
  // quad_perm [1,0,3,2] = 0xB1 : swap adjacent lanes (VALU pipe, not LDS)
  int r = __builtin_amdgcn_update_dpp(0, __builtin_bit_cast(int, x), 0xB1, 0xF, 0xF, true);
  return __builtin_bit_cast(float, r);
}

__global__ __launch_bounds__(512, 1)
void gru_scan2(const unsigned int* __restrict__ wscan,  // [12][3][128][256]
               const float* __restrict__ bias4,         // [12][4][256]
               const __half* __restrict__ xg,           // [2][M][768]
               const float* __restrict__ h0,            // [12][64][256]
               unsigned short* __restrict__ yout,       // [M][512] bf16 (next-layer input)
               float* __restrict__ dout,                // d_out base (f32)
               int layer, int last) {
  const int tid  = threadIdx.x;
  const int j    = tid >> 1;   // h column / gate triple owner
  const int half = tid & 1;    // K-half
  const int b    = blockIdx.x; // batch
  const int d    = blockIdx.y; // direction
  const int ld   = layer * 2 + d;

  // w_hh rows (r,z,n for column j, k-half) -> 192 u32 in registers
  unsigned int wr[64], wz[64], wn_[64];
  {
    const unsigned int* wb = wscan + (size_t)ld * 98304 + (size_t)half * 64 * 256 + j;
#pragma unroll
    for (int r = 0; r < 64; r++) wr[r]  = wb[r * 256];
#pragma unroll
    for (int r = 0; r < 64; r++) wz[r]  = wb[32768 + r * 256];
#pragma unroll
    for (int r = 0; r < 64; r++) wn_[r] = wb[65536 + r * 256];
  }
  // Opaque redefinition: blocks load-rematerialization.
#pragma unroll
  for (int r = 0; r < 64; r++) {
    asm volatile("" : "+v"(wr[r]));
    asm volatile("" : "+v"(wz[r]));
    asm volatile("" : "+v"(wn_[r]));
  }

  const float* bb = bias4 + ld * 1024;
  const float bR = bb[j], bZ = bb[256 + j], bXn = bb[512 + j], bHn = bb[768 + j];

  __shared__ __attribute__((aligned(16))) char hbc[2][512];

  // swizzled byte offset for h[j] (upper 256B block gets bit4 flipped)
  const int wboff = (j * 2) ^ ((j & 128) >> 3);

  float h = h0[(size_t)ld * 16384 + b * 256 + j];
  if (half == 0) *(unsigned short*)(hbc[0] + wboff) = __half_as_ushort(__float2half(h));

  const __half* xgd = xg + (size_t)d * M_ * 768;
  const int t0 = d ? 511 : 0;
  size_t xb = (size_t)(t0 * 64 + b) * 768 + j;
  __half cxr = xgd[xb], cxz = xgd[xb + 256], cxn = xgd[xb + 512];

  const int halfoff = half << 8;

  __syncthreads();

#define RD(k) (*(const uint4*)(rb + halfoff + ((((k) ^ half)) << 4)))
#define DOT1(hv, q)                                          \
  {                                                          \
    ar = FDOT2(BC2((hv).x), BC2(wr[4*(q)+0]), ar);           \
    az = FDOT2(BC2((hv).x), BC2(wz[4*(q)+0]), az);           \
    an = FDOT2(BC2((hv).x), BC2(wn_[4*(q)+0]), an);          \
    ar = FDOT2(BC2((hv).y), BC2(wr[4*(q)+1]), ar);           \
    az = FDOT2(BC2((hv).y), BC2(wz[4*(q)+1]), az);           \
    an = FDOT2(BC2((hv).y), BC2(wn_[4*(q)+1]), an);          \
    ar = FDOT2(BC2((hv).z), BC2(wr[4*(q)+2]), ar);           \
    az = FDOT2(BC2((hv).z), BC2(wz[4*(q)+2]), az);           \
    an = FDOT2(BC2((hv).z), BC2(wn_[4*(q)+2]), an);          \
    ar = FDOT2(BC2((hv).w), BC2(wr[4*(q)+3]), ar);           \
    az = FDOT2(BC2((hv).w), BC2(wz[4*(q)+3]), az);           \
    an = FDOT2(BC2((hv).w), BC2(wn_[4*(q)+3]), an);          \
  }
// Fence tied to the accumulators: orders memory ops AND forces the preceding
// DOT block to retire first -> loads/DOTs interleave, in-flight lines <= ~5.
#define AFENCE asm volatile("" : "+v"(ar), "+v"(az), "+v"(an) :: "memory")

  for (int s = 0; s < 512; s++) {
    const int cur = s & 1;
    // prefetch next step's xg
    const int sn = (s + 1) & 511;
    const int t1 = d ? 511 - sn : sn;
    const size_t xb1 = (size_t)(t1 * 64 + b) * 768 + j;
    const __half nxr = xgd[xb1], nxz = xgd[xb1 + 256], nxn = xgd[xb1 + 512];

    float ar = 0.f, az = 0.f, an = 0.f;
    const char* rb = hbc[cur];

    uint4 lA = RD(0), lB = RD(1), lC = RD(2), lD = RD(3);
    AFENCE;
    DOT1(lA, 0);  AFENCE; lA = RD(4);
    DOT1(lB, 1);  AFENCE; lB = RD(5);
    DOT1(lC, 2);  AFENCE; lC = RD(6);
    DOT1(lD, 3);  AFENCE; lD = RD(7);
    DOT1(lA, 4);  AFENCE; lA = RD(8);
    DOT1(lB, 5);  AFENCE; lB = RD(9);
    DOT1(lC, 6);  AFENCE; lC = RD(10);
    DOT1(lD, 7);  AFENCE; lD = RD(11);
    DOT1(lA, 8);  AFENCE; lA = RD(12);
    DOT1(lB, 9);  AFENCE; lB = RD(13);
    DOT1(lC, 10); AFENCE; lC = RD(14);
    DOT1(lD, 11); AFENCE; lD = RD(15);
    DOT1(lA, 12); AFENCE;
    DOT1(lB, 13); AFENCE;
    DOT1(lC, 14); AFENCE;
    DOT1(lD, 15);

    // combine K-halves: partner is the adjacent lane
    ar += dpp_xor1(ar);
    az += dpp_xor1(az);
    an += dpp_xor1(an);

    const float prer = ar + __half2float(cxr) + bR;
    const float prez = az + __half2float(cxz) + bZ;
    const float r = __builtin_amdgcn_rcpf(1.f + __builtin_amdgcn_exp2f(-1.44269504f * prer));
    const float z = __builtin_amdgcn_rcpf(1.f + __builtin_amdgcn_exp2f(-1.44269504f * prez));
    const float pren = __half2float(cxn) + bXn + r * (an + bHn);
    const float e2 = __builtin_amdgcn_exp2f(2.88539008f * pren);
    const float n = 1.f - 2.f * __builtin_amdgcn_rcpf(e2 + 1.f);
    h = n + z * (h - n);

    if (half == 0) {
      *(unsigned short*)(hbc[cur ^ 1] + wboff) = __half_as_ushort(__float2half(h));
      const int t = d ? 511 - s : s;
      const size_t orow = (size_t)(t * 64 + b) * 512 + (size_t)d * 256 + j;
      if (last) {
        dout[orow] = h;
      } else {
        unsigned u = __builtin_bit_cast(unsigned, h);
        u += 0x7fffu + ((u >> 16) & 1u);
        yout[orow] = (unsigned short)(u >> 16);
      }
    }
    cxr = nxr; cxz = nxz; cxn = nxn;
    __syncthreads();
  }
#undef RD
#undef DOT1
#undef AFENCE
  // final hidden state -> h_n region
  if (half == 0) dout[16777216 + (size_t)ld * 16384 + b * 256 + j] = h;
}

// ---------------- launcher ----------------
extern "C" void kernel_launch(void* const* d_in, const int* in_sizes, int n_in,
                              void* d_out, int out_size, void* d_ws, size_t ws_size,
                              hipStream_t stream) {
  const float* x    = (const float*)d_in[0];
  const float* h0   = (const float*)d_in[1];
  const float* wih0 = (const float*)d_in[2];
  const float* whh0 = (const float*)d_in[3];
  const float* bih0 = (const float*)d_in[4];
  const float* bhh0 = (const float*)d_in[5];
  const float* wihr = (const float*)d_in[6];
  const float* whhr = (const float*)d_in[7];
  const float* bihr = (const float*)d_in[8];
  const float* bhhr = (const float*)d_in[9];

  char* ws = (char*)d_ws;
  __half*        xg    = (__half*)(ws + XG_OFF);
  unsigned short* x0   = (unsigned short*)(ws + X0_OFF);
  unsigned short* yA   = (unsigned short*)(ws + YA_OFF);
  unsigned short* yB   = (unsigned short*)(ws + YB_OFF);
  unsigned short* wih0b= (unsigned short*)(ws + WIH0_OFF);
  unsigned short* wihrb= (unsigned short*)(ws + WIHR_OFF);
  unsigned int*  wscan = (unsigned int*)(ws + WSCAN_OFF);
  float*         bias4 = (float*)(ws + BIAS_OFF);
  float*         dout  = (float*)d_out;

  cvt_bf16<<<4096, 256, 0, stream>>>(x, x0, M_ * I_);
  cvt_bf16<<<768, 256, 0, stream>>>(wih0, wih0b, 2 * 768 * 128);
  cvt_bf16<<<4096, 256, 0, stream>>>(wihr, wihrb, 5 * 2 * 768 * 512);
  prep_wscan<<<4608, 256, 0, stream>>>(whh0, whhr, wscan);
  prep_bias<<<48, 256, 0, stream>>>(bih0, bhh0, bihr, bhhr, bias4);

  for (int l = 0; l < L_; l++) {
    unsigned short* yw = (l & 1) ? yB : yA;                        // scan l writes
    const unsigned short* A = (l == 0) ? x0 : ((l & 1) ? yA : yB); // gemm l reads scan l-1's out
    const int K = (l == 0) ? 128 : 512;
    const unsigned short* W = (l == 0) ? wih0b : wihrb + (size_t)(l - 1) * 2 * 768 * 512;

    gemm_bt<<<dim3(256, 6, 2), 256, 0, stream>>>(A, W, xg, K);
    gru_scan2<<<dim3(64, 2), 512, 0, stream>>>(wscan, bias4, xg, h0, yw, dout, l, l == L_ - 1);
  }
}